// Round 12
// baseline (215.226 us; speedup 1.0000x reference)
//
#include <hip/hip_runtime.h>
#include <hip/hip_bf16.h>

#define BB 4
#define LL 2048
#define DD 512
#define DKK 256

typedef __bf16 bf16;
typedef __bf16 bf16x4 __attribute__((ext_vector_type(4)));
typedef __bf16 bf16x8 __attribute__((ext_vector_type(8)));
typedef float f32x4 __attribute__((ext_vector_type(4)));

__device__ __forceinline__ void async_ld16(const bf16* g, bf16* l) {
    __builtin_amdgcn_global_load_lds(
        (const __attribute__((address_space(1))) void*)g,
        (__attribute__((address_space(3))) void*)l, 16, 0, 0);
}

// R19: ALL prep work in one flat-grid launch.  Region map (256-thread blocks):
//   [0,12288)      : Xq/Xk/Xv f32->bf16 (4096 each, exact cover)
//   [12288,12800)  : E f32->bf16 (512)
//   [12800,12928)  : W transposes, TILED (64x64 via LDS, both sides coalesced):
//                    [12800,12832) Wq (4x8 tiles), [12832,12864) Wk,
//                    [12864,12928) Wv (8x8 tiles)
// R18's W-transpose wrote 2B at 1KB stride (~16x write amplification);
// the tiled version writes bf16x8 contiguous runs.
__global__ void prep_all(const float* __restrict__ inQ, const float* __restrict__ inK,
                         const float* __restrict__ inV, const float* __restrict__ E,
                         const float* __restrict__ Wq, const float* __restrict__ Wk,
                         const float* __restrict__ Wv,
                         bf16* __restrict__ Xq, bf16* __restrict__ Xk,
                         bf16* __restrict__ Xv, bf16* __restrict__ Eb,
                         bf16* __restrict__ WqT, bf16* __restrict__ WkT,
                         bf16* __restrict__ WvT)
{
    __shared__ bf16 t[64][72];
    int bid = blockIdx.x;
    int tidx = threadIdx.x;
    if (bid < 12288) {
        int region = bid >> 12;
        int i = (bid & 4095) * 256 + tidx;         // 4096*256 == (B*L*D)/4 exact
        const float* in = (region == 0) ? inQ : (region == 1) ? inK : inV;
        bf16* out = (region == 0) ? Xq : (region == 1) ? Xk : Xv;
        f32x4 v = *(const f32x4*)(in + (size_t)i * 4);
        bf16x4 o;
        #pragma unroll
        for (int j = 0; j < 4; ++j) o[j] = (bf16)v[j];
        *(bf16x4*)(out + (size_t)i * 4) = o;
    } else if (bid < 12800) {
        int i = (bid - 12288) * 256 + tidx;        // 512*256 == (L*DK)/4 exact
        f32x4 v = *(const f32x4*)(E + (size_t)i * 4);
        bf16x4 o;
        #pragma unroll
        for (int j = 0; j < 4; ++j) o[j] = (bf16)v[j];
        *(bf16x4*)(Eb + (size_t)i * 4) = o;
    } else {
        // tiled transpose: in f32 [R][C] -> out bf16 [C][R]
        int tt = bid - 12800;
        const float* in;
        bf16* outp;
        int R, C, bx, by;
        if (tt < 32)      { in = Wq; outp = WqT; R = DD; C = DKK; tt -= 0;  bx = tt & 3; by = tt >> 2; }
        else if (tt < 64) { in = Wk; outp = WkT; R = DD; C = DKK; tt -= 32; bx = tt & 3; by = tt >> 2; }
        else              { in = Wv; outp = WvT; R = DD; C = DD;  tt -= 64; bx = tt & 7; by = tt >> 3; }
        int r = tidx >> 2, cc = (tidx & 3) * 16;
        const float* src = in + (size_t)(by * 64 + r) * C + bx * 64 + cc;
        #pragma unroll
        for (int u = 0; u < 16; u += 4) {
            f32x4 v = *(const f32x4*)(src + u);
            #pragma unroll
            for (int j = 0; j < 4; ++j) t[cc + u + j][r] = (bf16)v[j];
        }
        __syncthreads();
        bf16* dst = outp + (size_t)(bx * 64 + r) * R + by * 64 + cc;
        *(bf16x8*)dst = *(const bf16x8*)&t[r][cc];
        *(bf16x8*)(dst + 8) = *(const bf16x8*)&t[r][cc + 8];
    }
}

// Merged Q/K/V projection GEMM, R18 structure (proven): K-step double-buffer
// with ONE-AHEAD staging, BK=64, one barrier per step.  512 blocks = exactly
// 2/CU fully resident.  tbuf aliases Als[0] (nsteps=8 even -> dead at epilogue).
__launch_bounds__(256, 2)
__global__ void gemm_qkv(const bf16* __restrict__ Xq, const bf16* __restrict__ WqT,
                         bf16* __restrict__ Qw,
                         const bf16* __restrict__ Xk, const bf16* __restrict__ WkT,
                         bf16* __restrict__ Kw,
                         const bf16* __restrict__ Xv, const bf16* __restrict__ WvT,
                         bf16* __restrict__ Vt)
{
    __shared__ bf16 Als[2][2][128 * 32];   // [buf][sub][...]  32 KB
    __shared__ bf16 Bls[2][2][128 * 32];   // 32 KB

    int tid  = threadIdx.x;
    int lane = tid & 63;
    int wid  = tid >> 6;
    int l15  = lane & 15;
    int quad = lane >> 4;

    int bid  = blockIdx.x;
    int mode = (bid < 128) ? 0 : (bid < 256) ? 1 : 2;
    int idx  = bid - ((mode == 0) ? 0 : (mode == 1) ? 128 : 256);
    int nb   = (mode == 2) ? 4 : 2;
    int gx = idx % nb;
    int gy = idx / nb;
    int N  = (mode == 2) ? DD : DKK;
    const bf16* A  = (mode == 0) ? Xq  : (mode == 1) ? Xk  : Xv;
    const bf16* Bw = (mode == 0) ? WqT : (mode == 1) ? WkT : WvT;
    const int K = DD;

    const bf16* Ab = A + (size_t)gy * 128 * K;
    const bf16* Bb = Bw + (size_t)gx * 128 * K;

    int rl = lane >> 2;
    int sl = lane & 3;
    int half = wid & 1;
    const bf16* gsrc = (wid < 2) ? Ab : Bb;
    bf16 (*ls)[2][128 * 32] = (wid < 2) ? Als : Bls;   // this wave's staging dest

    const bf16* gptr[4];
    #pragma unroll
    for (int u = 0; u < 4; ++u) {
        int inst = half * 4 + u;
        int row  = inst * 16 + rl;
        int c    = (sl - (row >> 1)) & 3;
        gptr[u] = gsrc + (size_t)row * K + c * 8;
    }

#define STAGE_G(P) do {                                                    \
    _Pragma("unroll")                                                      \
    for (int u_ = 0; u_ < 4; ++u_) {                                       \
        async_ld16(gptr[u_],      &ls[P][0][(half * 4 + u_) * 512]);       \
        async_ld16(gptr[u_] + 32, &ls[P][1][(half * 4 + u_) * 512]);       \
        gptr[u_] += 64;                                                    \
    } } while (0)

    f32x4 acc[4][4];
    #pragma unroll
    for (int i = 0; i < 4; ++i)
        #pragma unroll
        for (int j = 0; j < 4; ++j) acc[i][j] = 0;

    const int nsteps = K / 64;   // 8 (even: tbuf aliasing of Als[0] is safe)
    STAGE_G(0);
    __syncthreads();
    for (int s = 0; s < nsteps; ++s) {
        int cur = s & 1;
        if (s + 1 < nsteps) STAGE_G(cur ^ 1);      // one-ahead, in flight
        #pragma unroll
        for (int h2 = 0; h2 < 2; ++h2) {
            bf16x8 fA[4], fB[4];
            #pragma unroll
            for (int rt = 0; rt < 4; ++rt) {
                int row = (wid & 1) * 64 + rt * 16 + l15;
                int sx  = (quad + (row >> 1)) & 3;
                fA[rt] = *(const bf16x8*)&Als[cur][h2][row * 32 + sx * 8];
            }
            #pragma unroll
            for (int ct = 0; ct < 4; ++ct) {
                int col = (wid >> 1) * 64 + ct * 16 + l15;
                int sx  = (quad + (col >> 1)) & 3;
                fB[ct] = *(const bf16x8*)&Bls[cur][h2][col * 32 + sx * 8];
            }
            #pragma unroll
            for (int rt = 0; rt < 4; ++rt)
                #pragma unroll
                for (int ct = 0; ct < 4; ++ct)
                    acc[rt][ct] = __builtin_amdgcn_mfma_f32_16x16x32_bf16(
                                      fA[rt], fB[ct], acc[rt][ct], 0, 0, 0);
        }
        if (s + 1 < nsteps || mode == 2) __syncthreads();
        // (modes 0/1: register epilogue, no LDS reuse -> last barrier skipped)
    }
#undef STAGE_G

    if (mode == 2) {
        // C^T -> Vt[n][m] via tbuf bounce; tbuf aliases Als[0] (17.4KB <= 32KB)
        bf16* tbuf = &Als[0][0][0];
        #pragma unroll
        for (int p = 0; p < 2; ++p) {
            if ((wid >> 1) == p) {
                #pragma unroll
                for (int rt = 0; rt < 4; ++rt)
                    #pragma unroll
                    for (int ct = 0; ct < 4; ++ct)
                        #pragma unroll
                        for (int r = 0; r < 4; ++r)
                            tbuf[(ct * 16 + l15) * 136
                                 + (wid & 1) * 64 + rt * 16 + quad * 4 + r]
                                = (bf16)acc[rt][ct][r];
            }
            __syncthreads();
            int row = tid >> 2, c0 = (tid & 3) * 32;
            bf16* dst = Vt + (size_t)(gx * 128 + p * 64 + row) * (BB * LL)
                           + (size_t)gy * 128 + c0;
            #pragma unroll
            for (int q = 0; q < 4; ++q)
                *(bf16x8*)(dst + q * 8) = *(const bf16x8*)&tbuf[row * 136 + c0 + q * 8];
            __syncthreads();
        }
    } else {
        bf16* Cb = (mode == 0) ? Qw : Kw;
        int m0 = gy * 128 + (wid & 1) * 64;
        int n0 = gx * 128 + (wid >> 1) * 64;
        #pragma unroll
        for (int rt = 0; rt < 4; ++rt)
            #pragma unroll
            for (int ct = 0; ct < 4; ++ct)
                #pragma unroll
                for (int r = 0; r < 4; ++r) {
                    int m = m0 + rt * 16 + quad * 4 + r;
                    int n = n0 + ct * 16 + l15;
                    Cb[(size_t)m * N + n] = (bf16)acc[rt][ct][r];
                }
    }
}

// Srel GEMM, R19: 4 BLOCKS/CU.  BK=32 one-ahead double-buffer (LDS 32 KB),
// __launch_bounds__(256,4) -> 1024 blocks all resident (4/CU, 16 waves/CU).
// Each block is prologue-latency-bound (only 8 short K-steps); block-level TLP
// now hides one block's prologue/epilogue under a neighbor's compute.  Unlike
// R16's attn occupancy attempt, GEMM blocks share operand panels through L2 --
// no intra-block read duplication penalty.  Skew scatter epilogue unchanged
// (writes are 32B-contiguous runs per 16 lanes -- no amplification).
__launch_bounds__(256, 4)
__global__ void gemm_srel(const bf16* __restrict__ A, const bf16* __restrict__ B,
                          bf16* __restrict__ C, long aStride, long cStride)
{
    __shared__ bf16 Als[2][128 * 32];
    __shared__ bf16 Bls[2][128 * 32];

    int tid  = threadIdx.x;
    int lane = tid & 63;
    int wid  = tid >> 6;
    int l15  = lane & 15;
    int quad = lane >> 4;
    const int N = LL, K = DKK;
    int nb = N >> 7;
    int gx = blockIdx.x % nb;
    int gy = blockIdx.x / nb;

    const bf16* Ab = A + (size_t)blockIdx.y * aStride + (size_t)gy * 128 * K;
    const bf16* Bb = B + (size_t)gx * 128 * K;

    int rl = lane >> 2;
    int sl = lane & 3;
    int half = wid & 1;
    const bf16* gsrc = (wid < 2) ? Ab : Bb;
    bf16 (*ls)[128 * 32] = (wid < 2) ? Als : Bls;

    const bf16* gptr[4];
    #pragma unroll
    for (int u = 0; u < 4; ++u) {
        int inst = half * 4 + u;
        int row  = inst * 16 + rl;
        int c    = (sl - (row >> 1)) & 3;
        gptr[u] = gsrc + (size_t)row * K + c * 8;
    }

#define STAGE_S(P) do {                                                    \
    _Pragma("unroll")                                                      \
    for (int u_ = 0; u_ < 4; ++u_) {                                       \
        async_ld16(gptr[u_], &ls[P][(half * 4 + u_) * 512]);               \
        gptr[u_] += 32;                                                    \
    } } while (0)

    f32x4 acc[4][4];
    #pragma unroll
    for (int i = 0; i < 4; ++i)
        #pragma unroll
        for (int j = 0; j < 4; ++j) acc[i][j] = 0;

    const int nsteps = K / 32;   // 8
    STAGE_S(0);
    __syncthreads();
    for (int s = 0; s < nsteps; ++s) {
        int cur = s & 1;
        if (s + 1 < nsteps) STAGE_S(cur ^ 1);      // one-ahead, in flight
        bf16x8 fA[4], fB[4];
        #pragma unroll
        for (int rt = 0; rt < 4; ++rt) {
            int row = (wid & 1) * 64 + rt * 16 + l15;
            int sx  = (quad + (row >> 1)) & 3;
            fA[rt] = *(const bf16x8*)&Als[cur][row * 32 + sx * 8];
        }
        #pragma unroll
        for (int ct = 0; ct < 4; ++ct) {
            int col = (wid >> 1) * 64 + ct * 16 + l15;
            int sx  = (quad + (col >> 1)) & 3;
            fB[ct] = *(const bf16x8*)&Bls[cur][col * 32 + sx * 8];
        }
        #pragma unroll
        for (int rt = 0; rt < 4; ++rt)
            #pragma unroll
            for (int ct = 0; ct < 4; ++ct)
                acc[rt][ct] = __builtin_amdgcn_mfma_f32_16x16x32_bf16(
                                  fA[rt], fB[ct], acc[rt][ct], 0, 0, 0);
        if (s + 1 < nsteps) __syncthreads();
        // (register epilogue: last barrier skipped)
    }
#undef STAGE_S

    bf16* Cb = C + (size_t)blockIdx.y * cStride;
    int m0 = gy * 128 + (wid & 1) * 64;
    int n0 = gx * 128 + (wid >> 1) * 64;
    #pragma unroll
    for (int rt = 0; rt < 4; ++rt)
        #pragma unroll
        for (int ct = 0; ct < 4; ++ct)
            #pragma unroll
            for (int r = 0; r < 4; ++r) {
                int row = m0 + rt * 16 + quad * 4 + r;
                int c   = n0 + ct * 16 + l15;
                bool lower = (c >= LL - 1 - row);
                int dr = lower ? row : row - 1;
                int dc = lower ? c - (LL - 1 - row) : c + row + 1;
                if (lower || row >= 1)
                    Cb[(size_t)dr * LL + dc] = (bf16)acc[rt][ct][r];
            }
}

// Fused attention: R13 structure (best-measured, ~86us) -- untouched.
// 4 waves / 256 threads, one-ahead split staging with counted vmcnt,
// pointer-increment staging addresses, Ss-LDS softmax.
__launch_bounds__(256, 2)
__global__ void attn_kernel(const bf16* __restrict__ Qw, const bf16* __restrict__ Kw,
                            const bf16* __restrict__ Vt, const bf16* __restrict__ Srel,
                            float* __restrict__ out)
{
    __shared__ bf16  Klds[64 * 256];      // rows j (64), 32 chunks of 8, rotated
    __shared__ bf16  Vlds[256 * 64];      // rows d (256), 8 chunks of 8, rotated
    __shared__ float Ss[32][68];
    __shared__ bf16  Ps[32][72];
    __shared__ float mSt[32], lSt[32], aSt[32];

    int tid  = threadIdx.x;
    int lane = tid & 63;
    int wid  = tid >> 6;
    int l15  = lane & 15;
    int quad = lane >> 4;

    int xcd = blockIdx.x & 7;          // XCD = blockIdx % 8 (round-robin dispatch)
    int b   = xcd >> 1;
    int dh  = xcd & 1;
    int i0  = (blockIdx.x >> 3) * 32;

    const bf16* Qb = Qw + (size_t)b * LL * DKK;
    const bf16* Kb = Kw + (size_t)b * LL * DKK;
    const bf16* Sb = Srel + (size_t)b * LL * LL;
    const bf16* Vb = Vt + (size_t)(dh * 256) * (BB * LL) + (size_t)b * LL;

    // persistent staging pointers (wave-local rows), bumped per iteration
    const bf16* kptr[8];
    const bf16* vptr[8];
    #pragma unroll
    for (int u = 0; u < 8; ++u) {
        int inst = wid * 8 + u;
        int j_ = inst * 2 + (lane >> 5);
        int ck = ((lane & 31) - j_) & 31;
        kptr[u] = Kb + (size_t)j_ * DKK + ck * 8;
        int d_ = inst * 8 + (lane >> 3);
        int cv = ((lane & 7) - d_) & 7;
        vptr[u] = Vb + (size_t)d_ * (BB * LL) + cv * 8;
    }

    bf16x8 Qreg[2][8];
    #pragma unroll
    for (int rt = 0; rt < 2; ++rt)
        #pragma unroll
        for (int ks = 0; ks < 8; ++ks)
            Qreg[rt][ks] = *(const bf16x8*)(Qb + (size_t)(i0 + rt * 16 + l15) * DKK
                                            + ks * 32 + quad * 8);

    if (tid < 32) { mSt[tid] = -1e30f; lSt[tid] = 0.f; }

    f32x4 accO[2][4];
    #pragma unroll
    for (int rt = 0; rt < 2; ++rt)
        #pragma unroll
        for (int nt = 0; nt < 4; ++nt) accO[rt][nt] = 0;

    // drain Qreg loads before the counted staging stream starts
    asm volatile("s_waitcnt vmcnt(0)" ::: "memory");

    // ---- prologue (issue order defines vmcnt counts): K0(8), srel0(1), V0(8)
    #pragma unroll
    for (int u = 0; u < 8; ++u) {
        async_ld16(kptr[u], Klds + (wid * 8 + u) * 512);
        kptr[u] += 64 * DKK;
    }
    __builtin_amdgcn_sched_barrier(0);
    int srow = i0 + (tid >> 3), ssg = tid & 7;
    bf16x8 srelCur = *(const bf16x8*)(Sb + (size_t)srow * LL + ssg * 8);
    const bf16* sPtr = Sb + (size_t)srow * LL + ssg * 8 + 64;
    __builtin_amdgcn_sched_barrier(0);
    #pragma unroll
    for (int u = 0; u < 8; ++u) {
        async_ld16(vptr[u], Vlds + (wid * 8 + u) * 512);
        vptr[u] += 64;
    }

    int jrow = wid * 16 + l15;

    for (int j0 = 0; j0 < LL; j0 += 64) {
        bool notlast = (j0 + 64 < LL);

        // ===== QK phase =====
        asm volatile("s_waitcnt vmcnt(9)" ::: "memory");   // K(i) staged
        bf16x8 kf[8];
        #pragma unroll
        for (int ks = 0; ks < 8; ++ks) {
            int cp = (ks * 4 + quad + jrow) & 31;
            kf[ks] = *(const bf16x8*)&Klds[jrow * 256 + cp * 8];
        }
        asm volatile("s_waitcnt lgkmcnt(0)" ::: "memory"); // own kf reads done
        __builtin_amdgcn_sched_barrier(0);
        if (notlast) {                                     // K(i+1) in flight
            #pragma unroll
            for (int u = 0; u < 8; ++u) {
                async_ld16(kptr[u], Klds + (wid * 8 + u) * 512);
                kptr[u] += 64 * DKK;
            }
        }
        __builtin_amdgcn_sched_barrier(0);
        bf16x8 srelNext;
        if (notlast) {                                     // srel(i+1) in flight
            srelNext = *(const bf16x8*)sPtr;
            sPtr += 64;
        }
        __builtin_amdgcn_sched_barrier(0);
        f32x4 s0 = 0, s1 = 0;
        __builtin_amdgcn_s_setprio(1);
        #pragma unroll
        for (int ks = 0; ks < 8; ++ks) {
            s0 = __builtin_amdgcn_mfma_f32_16x16x32_bf16(Qreg[0][ks], kf[ks], s0, 0, 0, 0);
            s1 = __builtin_amdgcn_mfma_f32_16x16x32_bf16(Qreg[1][ks], kf[ks], s1, 0, 0, 0);
        }
        __builtin_amdgcn_s_setprio(0);
        #pragma unroll
        for (int r = 0; r < 4; ++r) {
            Ss[quad * 4 + r][wid * 16 + l15]      = s0[r];
            Ss[16 + quad * 4 + r][wid * 16 + l15] = s1[r];
        }
        asm volatile("s_waitcnt lgkmcnt(0)\ns_barrier" ::: "memory");   // b2: Ss handoff

        // ===== softmax =====
        {
            int r = tid >> 3, sg = tid & 7;
            int i = i0 + r;
            float v[8];
            #pragma unroll
            for (int c = 0; c < 8; ++c) {
                float sr = (j0 + sg * 8 + c == i + 1) ? 0.f : (float)srelCur[c];
                v[c] = (Ss[r][sg * 8 + c] + sr) * 0.0625f;
            }
            float tmax = v[0];
            #pragma unroll
            for (int c = 1; c < 8; ++c) tmax = fmaxf(tmax, v[c]);
            tmax = fmaxf(tmax, __shfl_xor(tmax, 1));
            tmax = fmaxf(tmax, __shfl_xor(tmax, 2));
            tmax = fmaxf(tmax, __shfl_xor(tmax, 4));
            float mOld = mSt[r], lOld = lSt[r];
            float mNew = fmaxf(mOld, tmax);
            float alpha = __expf(mOld - mNew);
            float ps = 0.f;
            bf16x8 pv;
            #pragma unroll
            for (int c = 0; c < 8; ++c) {
                float p = __expf(v[c] - mNew);
                ps += p;
                pv[c] = (bf16)p;
            }
            ps += __shfl_xor(ps, 1);
            ps += __shfl_xor(ps, 2);
            ps += __shfl_xor(ps, 4);
            *(bf16x8*)&Ps[r][sg * 8] = pv;
            if (sg == 0) { mSt[r] = mNew; lSt[r] = alpha * lOld + ps; aSt[r] = alpha; }
        }
        srelCur = srelNext;
        asm volatile("s_waitcnt lgkmcnt(0)\ns_barrier" ::: "memory");   // b3: Ps handoff

        // ===== PV phase =====
        if (notlast) asm volatile("s_waitcnt vmcnt(9)" ::: "memory");   // V(i) staged
        else         asm volatile("s_waitcnt vmcnt(0)" ::: "memory");
        bf16x8 aF[2][2];
        #pragma unroll
        for (int rt = 0; rt < 2; ++rt)
            #pragma unroll
            for (int kk = 0; kk < 2; ++kk)
                aF[rt][kk] = *(const bf16x8*)&Ps[rt * 16 + l15][kk * 32 + quad * 8];
        float ar[2][4];
        #pragma unroll
        for (int rt = 0; rt < 2; ++rt)
            #pragma unroll
            for (int r = 0; r < 4; ++r) ar[rt][r] = aSt[rt * 16 + quad * 4 + r];
        bf16x8 vf[4][2];
        #pragma unroll
        for (int nt = 0; nt < 4; ++nt) {
            int dd = wid * 64 + nt * 16 + l15;
            int c0 = (quad + dd) & 7;
            int c1 = (4 + quad + dd) & 7;
            vf[nt][0] = *(const bf16x8*)&Vlds[dd * 64 + c0 * 8];
            vf[nt][1] = *(const bf16x8*)&Vlds[dd * 64 + c1 * 8];
        }
        asm volatile("s_waitcnt lgkmcnt(0)" ::: "memory"); // own Ps/vf reads done
        __builtin_amdgcn_sched_barrier(0);
        if (notlast) {                                     // V(i+1) in flight
            #pragma unroll
            for (int u = 0; u < 8; ++u) {
                async_ld16(vptr[u], Vlds + (wid * 8 + u) * 512);
                vptr[u] += 64;
            }
        }
        __builtin_amdgcn_sched_barrier(0);
        __builtin_amdgcn_s_setprio(1);
        #pragma unroll
        for (int nt = 0; nt < 4; ++nt) {
            #pragma unroll
            for (int rt = 0; rt < 2; ++rt) {
                f32x4 o = accO[rt][nt];
                o[0] *= ar[rt][0]; o[1] *= ar[rt][1];
                o[2] *= ar[rt][2]; o[3] *= ar[rt][3];
                o = __builtin_amdgcn_mfma_f32_16x16x32_bf16(aF[rt][0], vf[nt][0], o, 0, 0, 0);
                o = __builtin_amdgcn_mfma_f32_16x16x32_bf16(aF[rt][1], vf[nt][1], o, 0, 0, 0);
                accO[rt][nt] = o;
            }
        }
        __builtin_amdgcn_s_setprio(0);
        // no trailing barrier: Ss WAR covered by b3(i), Ps/aSt WAR by b2(i+1)
    }
    float lr[2][4];
    #pragma unroll
    for (int rt = 0; rt < 2; ++rt)
        #pragma unroll
        for (int r = 0; r < 4; ++r) lr[rt][r] = 1.f / lSt[rt * 16 + quad * 4 + r];
    #pragma unroll
    for (int rt = 0; rt < 2; ++rt)
        #pragma unroll
        for (int nt = 0; nt < 4; ++nt)
            #pragma unroll
            for (int r = 0; r < 4; ++r) {
                int i = i0 + rt * 16 + quad * 4 + r;
                int d = dh * 256 + wid * 64 + nt * 16 + l15;
                out[((size_t)b * LL + i) * DD + d] = accO[rt][nt][r] * lr[rt][r];
            }
}

extern "C" void kernel_launch(void* const* d_in, const int* in_sizes, int n_in,
                              void* d_out, int out_size, void* d_ws, size_t ws_size,
                              hipStream_t stream) {
    const float* inQ = (const float*)d_in[0];
    const float* inK = (const float*)d_in[1];
    const float* inV = (const float*)d_in[2];
    const float* Wq  = (const float*)d_in[3];
    const float* Wk  = (const float*)d_in[4];
    const float* Wv  = (const float*)d_in[5];
    const float* E   = (const float*)d_in[6];
    float* out = (float*)d_out;

    char* ws = (char*)d_ws;
    bf16* Qw   = (bf16*)(ws);                         // 4 MB  [B*L][DK]
    bf16* Kw   = (bf16*)(ws + ((size_t)4  << 20));    // 4 MB  [B*L][DK]
    bf16* Vt   = (bf16*)(ws + ((size_t)8  << 20));    // 8 MB  [D][B*L]
    bf16* SrelW= (bf16*)(ws + ((size_t)16 << 20));    // 32 MB [B,L,L] skewed
    bf16* Xq   = (bf16*)(ws + ((size_t)16 << 20));    // 8 MB  (transient)
    bf16* Xk   = (bf16*)(ws + ((size_t)24 << 20));    // 8 MB
    bf16* Xv   = (bf16*)(ws + ((size_t)32 << 20));    // 8 MB
    bf16* WqT  = (bf16*)(ws + ((size_t)48 << 20));            // [DK][D]
    bf16* WkT  = (bf16*)(ws + ((size_t)48 << 20) + 262144);   // [DK][D]
    bf16* WvT  = (bf16*)(ws + ((size_t)48 << 20) + 524288);   // [D][D]
    bf16* Eb   = (bf16*)(ws + ((size_t)49 << 20));            // [L][DK]

    // all prep (3 activation convs + E conv + tiled W transposes): one launch
    prep_all<<<12928, 256, 0, stream>>>(inQ, inK, inV, E, Wq, Wk, Wv,
                                        Xq, Xk, Xv, Eb, WqT, WkT, WvT);
    // Q, K, V projections in ONE full-GPU launch (512 blocks)
    gemm_qkv<<<512, 256, 0, stream>>>(Xq, WqT, Qw, Xk, WkT, Kw, Xv, WvT, Vt);
    // Srel (skewed) = skew(Q·E^T): per-batch M=N=2048 K=256, 4 blocks/CU
    gemm_srel<<<dim3(16 * 16, BB), 256, 0, stream>>>(Qw, Eb, SrelW,
                                                     (long)LL * DKK, (long)LL * LL);
    attn_kernel<<<dim3(BB * 64 * 2), 256, 0, stream>>>(Qw, Kw, Vt, SrelW, out);
}